// Round 1
// baseline (95.049 us; speedup 1.0000x reference)
//
#include <hip/hip_runtime.h>

#define LH 8192
#define LG 128
#define LP 16
#define NFFT 16384
#define NMASK 16383

#define TWO_PI_OVER_N (6.28318530717958647692f / 16384.0f)

// ---------------- Kernel A: u = conv(x, g)[:LH] ----------------
__global__ __launch_bounds__(256) void conv_xg_kernel(
    const float* __restrict__ x, const float* __restrict__ g,
    float* __restrict__ u) {
  __shared__ float gs[LG];
  int tid = threadIdx.x;
  if (tid < LG) gs[tid] = g[tid];
  __syncthreads();
  int n = blockIdx.x * 256 + tid;
  if (n >= LH) return;
  float acc = 0.f;
  int jmax = n < (LG - 1) ? n : (LG - 1);
  for (int j = 0; j <= jmax; ++j) acc = fmaf(x[n - j], gs[j], acc);
  u[n] = acc;
}

// ------- Kernel B: xg[n] = u[n] + u[n-2] + ... (stride-2 prefix) -------
__global__ __launch_bounds__(256) void comb_prefix_kernel(
    const float* __restrict__ u, float* __restrict__ xg) {
  __shared__ float csum[256];
  __shared__ float coff[256];
  int tid = threadIdx.x;
  int pr = tid & 1;        // parity (even/odd subsequence)
  int c = tid >> 1;        // chunk id 0..127, chunk = 32 elements of subsequence
  float vals[32];
  float s = 0.f;
  for (int k = 0; k < 32; ++k) {
    s += u[2 * (c * 32 + k) + pr];
    vals[k] = s;  // inclusive prefix within chunk
  }
  csum[tid] = s;
  __syncthreads();
  if (tid < 2) {  // serial exclusive scan of 128 chunk sums per parity (tiny)
    float run = 0.f;
    for (int cc = 0; cc < 128; ++cc) {
      coff[cc * 2 + tid] = run;
      run += csum[cc * 2 + tid];
    }
  }
  __syncthreads();
  float off = coff[tid];
  for (int k = 0; k < 32; ++k) xg[2 * (c * 32 + k) + pr] = vals[k] + off;
}

// ------- Kernel C: Yf[n] = sum_k xg[k] * v[n]^k, n = 0..8192 -------
// One wave per bin. Lane l: Horner in w=v^64 over xg[64j+l], scale v^l, reduce.
__global__ __launch_bounds__(1024) void eval_Yf_kernel(
    const float* __restrict__ xg, const float* __restrict__ a_in,
    const float* __restrict__ p, float2* __restrict__ Yf) {
  __shared__ float xgs[LH];  // 32 KB
  int tid = threadIdx.x;
  for (int i = tid; i < LH; i += 1024) xgs[i] = xg[i];
  __syncthreads();
  int wave = tid >> 6;
  int lane = tid & 63;
  int n = blockIdx.x * 16 + wave;
  if (n > LH) return;  // bins 0..8192 inclusive

  float ea = __expf(a_in[0]);
  // P_f[n] = e^a * sum_j p[j] e^{-2pi i n j / N}
  float pr = 0.f, pi = 0.f;
  for (int j = 0; j < LP; ++j) {
    int m = (n * j) & NMASK;
    float s, cc;
    __sincosf((float)m * TWO_PI_OVER_N, &s, &cc);
    float pj = p[j];
    pr = fmaf(pj, cc, pr);
    pi = fmaf(pj, -s, pi);
  }
  pr *= ea;
  pi *= ea;
  // v = P_f * e^{-2pi i n / N}
  float s1, c1;
  __sincosf((float)(n & NMASK) * TWO_PI_OVER_N, &s1, &c1);
  float vr = fmaf(pr, c1, pi * s1);
  float vi = fmaf(pi, c1, -pr * s1);
  // powers v^(2^b), b = 0..6
  float pwr[7], pwi[7];
  pwr[0] = vr;
  pwi[0] = vi;
  for (int b = 1; b < 7; ++b) {
    float r = pwr[b - 1], ii = pwi[b - 1];
    pwr[b] = fmaf(r, r, -ii * ii);
    pwi[b] = 2.f * r * ii;
  }
  float wr = pwr[6], wi = pwi[6];  // w = v^64
  // Horner over 128 coefficients xgs[64j + lane], j = 127..0
  float ar = 0.f, ai = 0.f;
#pragma unroll 8
  for (int j = 127; j >= 0; --j) {
    float cj = xgs[(j << 6) + lane];
    float t = fmaf(ar, wr, fmaf(-ai, wi, cj));
    ai = fmaf(ar, wi, ai * wr);
    ar = t;
  }
  // scale = v^lane (binary exponentiation over lane bits)
  float sr = 1.f, si = 0.f;
  for (int b = 0; b < 6; ++b) {
    if ((lane >> b) & 1) {
      float t = fmaf(sr, pwr[b], -si * pwi[b]);
      si = fmaf(sr, pwi[b], si * pwr[b]);
      sr = t;
    }
  }
  float rr = fmaf(ar, sr, -ai * si);
  float ri = fmaf(ar, si, ai * sr);
  // wave reduction
  for (int o = 32; o > 0; o >>= 1) {
    rr += __shfl_down(rr, o, 64);
    ri += __shfl_down(ri, o, 64);
  }
  if (lane == 0) Yf[n] = make_float2(rr, ri);
}

// ------- Kernel D: y[t] = (2 Re sum_{n<8192} Yf[n] z^n - Yr0 + (-1)^t Yr8192)/N -------
// One wave per t. Lane l: Horner in w=z^64 over Yf[64j+l], scale z^l, reduce.
__global__ __launch_bounds__(1024) void eval_y_kernel(
    const float2* __restrict__ Yf, float* __restrict__ y) {
  __shared__ float2 yfs[LH];  // 64 KB
  int tid = threadIdx.x;
  for (int i = tid; i < LH; i += 1024) yfs[i] = Yf[i];
  __syncthreads();
  int wave = tid >> 6;
  int lane = tid & 63;
  int t = blockIdx.x * 16 + wave;  // 0..8191

  // w = z^64 = e^{+2pi i (64 t mod N)/N}
  float ws, wc;
  __sincosf((float)((t << 6) & NMASK) * TWO_PI_OVER_N, &ws, &wc);
  float wr = wc, wi = ws;
  // Horner over 128 complex coefficients yfs[64j + lane], j = 127..0
  float ar = 0.f, ai = 0.f;
#pragma unroll 8
  for (int j = 127; j >= 0; --j) {
    float2 C = yfs[(j << 6) + lane];
    float tt = fmaf(ar, wr, fmaf(-ai, wi, C.x));
    ai = fmaf(ar, wi, fmaf(ai, wr, C.y));
    ar = tt;
  }
  // scale = z^lane = e^{+2pi i (t*lane mod N)/N}
  float zs, zc;
  __sincosf((float)((t * lane) & NMASK) * TWO_PI_OVER_N, &zs, &zc);
  float rr = fmaf(ar, zc, -ai * zs);
  float ri = fmaf(ar, zs, ai * zc);
  // wave reduction
  for (int o = 32; o > 0; o >>= 1) {
    rr += __shfl_down(rr, o, 64);
    ri += __shfl_down(ri, o, 64);
  }
  if (lane == 0) {
    float Yr0 = Yf[0].x;
    float Yrh = Yf[LH].x;  // bin N/2 = 8192 (real by symmetry)
    float sign = (t & 1) ? -1.f : 1.f;
    y[t] = (2.f * rr - Yr0 + sign * Yrh) * (1.0f / (float)NFFT);
  }
}

extern "C" void kernel_launch(void* const* d_in, const int* in_sizes, int n_in,
                              void* d_out, int out_size, void* d_ws, size_t ws_size,
                              hipStream_t stream) {
  const float* x = (const float*)d_in[0];   // (8192,)
  const float* g = (const float*)d_in[1];   // (128,)
  const float* a = (const float*)d_in[2];   // scalar
  const float* p = (const float*)d_in[3];   // (16,)
  float* y = (float*)d_out;                 // (8192,) float32

  float* u = (float*)d_ws;                  // 8192 floats
  float* xg = u + LH;                       // 8192 floats
  float2* Yf = (float2*)(xg + LH);          // 8193 float2 (offset 64 KiB, aligned)

  conv_xg_kernel<<<32, 256, 0, stream>>>(x, g, u);
  comb_prefix_kernel<<<1, 256, 0, stream>>>(u, xg);
  eval_Yf_kernel<<<513, 1024, 0, stream>>>(xg, a, p, Yf);
  eval_y_kernel<<<512, 1024, 0, stream>>>(Yf, y);
}

// Round 2
// 85.703 us; speedup vs baseline: 1.1091x; 1.1091x over previous
//
#include <hip/hip_runtime.h>

#define LH 8192
#define LG 128
#define LP 16
#define NFFT 16384
#define M_HALF 8192
#define KTR 256   // truncation order: |v|^256 ~ 1e-20 (|v| ~ 0.64), threshold 2e-2

#define TWO_PI 6.28318530717958647692f
#define TWO_PI_OVER_N (TWO_PI / 16384.0f)

// ---- K1: xg[0..KTR-1] = (x * g * comb)[:KTR] = stride-2 prefix of u = conv(x,g) ----
__global__ __launch_bounds__(256) void xg_kernel(
    const float* __restrict__ x, const float* __restrict__ g,
    float* __restrict__ xg) {
  __shared__ float us[KTR];
  int n = threadIdx.x;  // 0..255
  float acc = 0.f;
  int jmax = n < (LG - 1) ? n : (LG - 1);
  for (int j = 0; j <= jmax; ++j) acc = fmaf(x[n - j], g[j], acc);
  us[n] = acc;
  __syncthreads();
  // stride-2 inclusive scan (Hillis-Steele, offsets 2,4,...,128 cover back-reach 254)
  for (int d = 2; d < KTR; d <<= 1) {
    float v = us[n];
    if (n >= d) v += us[n - d];
    __syncthreads();
    us[n] = v;
    __syncthreads();
  }
  xg[n] = us[n];
}

// ---- K2: Yf[n] = sum_{k<KTR} xg[k] v_n^k, n = 0..8192; v_n = e^a P(base) base ----
__global__ __launch_bounds__(256) void Yf_kernel(
    const float* __restrict__ xg, const float* __restrict__ a_in,
    const float* __restrict__ p, float2* __restrict__ Yf) {
  __shared__ float xs[KTR];
  __shared__ float ps[LP];
  int tid = threadIdx.x;
  xs[tid] = xg[tid];
  if (tid < LP) ps[tid] = p[tid];
  __syncthreads();
  int n = blockIdx.x * 256 + tid;
  if (n > M_HALF) return;  // bins 0..8192

  float ea = __expf(a_in[0]);
  float s, c;
  __sincosf((float)n * TWO_PI_OVER_N, &s, &c);
  float br = c, bi = -s;  // base = e^{-2pi i n/N}
  // P_f[n] = e^a * sum_j p[j] base^j  (Horner, j = 15..0)
  float pr = 0.f, pim = 0.f;
  for (int j = LP - 1; j >= 0; --j) {
    float t = fmaf(pr, br, fmaf(-pim, bi, ps[j]));
    pim = fmaf(pr, bi, pim * br);
    pr = t;
  }
  pr *= ea;
  pim *= ea;
  // v = P_f * base
  float vr = fmaf(pr, br, -pim * bi);
  float vi = fmaf(pr, bi, pim * br);
  // truncated Horner over xs[KTR-1 .. 0]
  float ar = 0.f, ai = 0.f;
#pragma unroll 8
  for (int k = KTR - 1; k >= 0; --k) {
    float t = fmaf(ar, vr, fmaf(-ai, vi, xs[k]));
    ai = fmaf(ar, vi, ai * vr);
    ar = t;
  }
  Yf[n] = make_float2(ar, ai);
}

// ---- K3: irfft stage 1. Pack Hermitian Yf -> W (length 8192), then for each
// k1 (block) a length-128 iDFT over k2 + twiddle:  G[k1,m2] =
// (1/M) e^{+2pi i k1 m2/8192} sum_{k2<128} W[k1+64 k2] e^{+2pi i k2 m2/128} ----
__global__ __launch_bounds__(128) void ifft_s1_kernel(
    const float2* __restrict__ Yf, float2* __restrict__ G) {
  __shared__ float2 Ws[128];
  __shared__ float2 r128[128];
  int k1 = blockIdx.x;   // 0..63
  int j = threadIdx.x;   // 0..127
  float s, c;
  __sincosf((float)j * (TWO_PI / 128.f), &s, &c);
  r128[j] = make_float2(c, s);  // e^{+2pi i j/128}
  // pack W[k], k = k1 + 64 j
  int k = k1 + 64 * j;  // 0..8191
  float2 Xk = Yf[k];
  float2 Xm = Yf[M_HALF - k];
  float er = 0.5f * (Xk.x + Xm.x);   // Xe = (X[k] + conj(X[M-k]))/2
  float ei = 0.5f * (Xk.y - Xm.y);
  float dr = 0.5f * (Xk.x - Xm.x);   // D = (X[k] - conj(X[M-k]))/2
  float di = 0.5f * (Xk.y + Xm.y);
  float ts, tc;
  __sincosf((float)k * TWO_PI_OVER_N, &ts, &tc);  // e^{+2pi i k/N}
  float xo_r = fmaf(dr, tc, -di * ts);
  float xo_i = fmaf(dr, ts, di * tc);
  // W = Xe + i*Xo
  Ws[j] = make_float2(er - xo_i, ei + xo_r);
  __syncthreads();
  int m2 = j;
  float gr = 0.f, gi = 0.f;
#pragma unroll 4
  for (int k2 = 0; k2 < 128; ++k2) {
    float2 w = Ws[k2];
    float2 r = r128[(k2 * m2) & 127];
    gr = fmaf(w.x, r.x, fmaf(-w.y, r.y, gr));
    gi = fmaf(w.x, r.y, fmaf(w.y, r.x, gi));
  }
  float tws, twc;
  __sincosf((float)(k1 * m2) * (TWO_PI / 8192.f), &tws, &twc);
  float Gr = fmaf(gr, twc, -gi * tws) * (1.f / 8192.f);
  float Gi = fmaf(gr, tws, gi * twc) * (1.f / 8192.f);
  G[k1 * 128 + m2] = make_float2(Gr, Gi);
}

// ---- K4: irfft stage 2 + unpack. w[m2+128 m1] = sum_{k1<64} G[k1,m2] e^{+2pi i k1 m1/64};
// y[2m] = Re w[m], y[2m+1] = Im w[m]  (only m1 < 32 needed for y[0..8191]) ----
__global__ __launch_bounds__(128) void ifft_s2_kernel(
    const float2* __restrict__ G, float2* __restrict__ yout) {
  int m1 = blockIdx.x;   // 0..31
  int m2 = threadIdx.x;  // 0..127
  __shared__ float2 r64[64];
  if (m2 < 64) {
    float s, c;
    __sincosf((float)((m2 * m1) & 63) * (TWO_PI / 64.f), &s, &c);
    r64[m2] = make_float2(c, s);  // e^{+2pi i k1 m1/64}
  }
  __syncthreads();
  float wr = 0.f, wi = 0.f;
#pragma unroll 4
  for (int k1 = 0; k1 < 64; ++k1) {
    float2 gv = G[k1 * 128 + m2];  // coalesced: lanes = consecutive m2
    float2 r = r64[k1];
    wr = fmaf(gv.x, r.x, fmaf(-gv.y, r.y, wr));
    wi = fmaf(gv.x, r.y, fmaf(gv.y, r.x, wi));
  }
  yout[m2 + 128 * m1] = make_float2(wr, wi);
}

extern "C" void kernel_launch(void* const* d_in, const int* in_sizes, int n_in,
                              void* d_out, int out_size, void* d_ws, size_t ws_size,
                              hipStream_t stream) {
  const float* x = (const float*)d_in[0];  // (8192,)
  const float* g = (const float*)d_in[1];  // (128,)
  const float* a = (const float*)d_in[2];  // scalar
  const float* p = (const float*)d_in[3];  // (16,)
  float2* yout = (float2*)d_out;           // 8192 floats viewed as 4096 float2

  char* ws = (char*)d_ws;
  float* xg = (float*)ws;                        // 256 floats   @ 0
  float2* Yf = (float2*)(ws + 1024);             // 8193 float2  @ 1 KiB
  float2* G = (float2*)(ws + 1024 + 65600);      // 8192 float2  (8-aligned)

  xg_kernel<<<1, 256, 0, stream>>>(x, g, xg);
  Yf_kernel<<<33, 256, 0, stream>>>(xg, a, p, Yf);
  ifft_s1_kernel<<<64, 128, 0, stream>>>(Yf, G);
  ifft_s2_kernel<<<32, 128, 0, stream>>>(G, yout);
}